// Round 12
// baseline (150.437 us; speedup 1.0000x reference)
//
#include <hip/hip_runtime.h>

#define T_FRAMES 1001
#define MEL_STRIDE 1008
#define P_STRIDE 268

// ws float offsets
#define OFF_WIN 0          // [416] f32
#define OFF_DCT 416        // [64][20] f32
#define OFF_BG  1696       // u16[13 ktile][16384] twiddles, chunked (106496 f)
#define OFF_FBG 108192     // u16[64 mel][264] (8448 f)
#define OFF_MEL 13748128   // f32 [4096][1008]

typedef unsigned int u32;
typedef unsigned short u16;
typedef __attribute__((ext_vector_type(8))) short bf16x8;
typedef __attribute__((ext_vector_type(4))) float f32x4;

__device__ __forceinline__ u16 f2bf(float f) {
  u32 u = __float_as_uint(f);
  u32 r = (u + 0x7FFFu + ((u >> 16) & 1u)) >> 16;
  return (u16)r;
}

__device__ __forceinline__ int reflect_idx(int g) {
  g = (g < 0) ? -g : g;
  g = (g >= 160000) ? (319998 - g) : g;
  return g;
}

__global__ __launch_bounds__(256) void k_init(float* __restrict__ ws) {
  float* win = ws + OFF_WIN;
  float* dct = ws + OFF_DCT;
  u16* bg = (u16*)(ws + OFF_BG);
  u16* fbg = (u16*)(ws + OFF_FBG);
  const float W = 6.28318530717958647692f / 400.0f;
  int tid = blockIdx.x * 256 + threadIdx.x;
  int stride = gridDim.x * 256;
  for (int i = tid; i < 416; i += stride)
    win[i] = (i < 400) ? (0.5f - 0.5f * cosf((float)i * W)) : 0.0f;
  for (int i = tid; i < 64 * 20; i += stride) {
    int m = i / 20, k = i % 20;
    float v = cosf(3.14159265358979323846f / 64.0f * ((float)m + 0.5f) * (float)k) * sqrtf(2.0f / 64.0f);
    if (k == 0) v *= 0.70710678118654752440f;
    dct[i] = v;
  }
  // twiddles, chunked: u16 index = kt*16384 + g*512 + khalf*128 + c15*8 + e
  for (int i = tid; i < 13 * 16384; i += stride) {
    int kt = i >> 14;
    int r = i & 16383;
    int g = r >> 9;
    int khalf = (r >> 7) & 3;
    int c15 = (r >> 3) & 15;
    int e = r & 7;
    int col = g * 16 + c15;
    int n = kt * 32 + khalf * 8 + e;
    int bin = ((col >> 5) << 4) | (col & 15);
    int type = (col >> 4) & 1;
    float v = 0.0f;
    if (n < 400 && bin <= 200) {
      float a = (float)((n * bin) % 400) * W;
      v = type ? -sinf(a) : cosf(a);
    }
    bg[i] = f2bf(v);
  }
  // mel filterbank [mel][264], zero past bin 200
  for (int i = tid; i < 64 * 264; i += stride) {
    int m = i / 264, f = i % 264;
    float v = 0.0f;
    if (f <= 200) {
      float freq = 40.0f * (float)f;
      float m_max = 2595.0f * log10f(1.0f + 8000.0f / 700.0f);
      float ms = m_max / 65.0f;
      float fp0 = 700.0f * (powf(10.0f, (float)(m)     * ms / 2595.0f) - 1.0f);
      float fp1 = 700.0f * (powf(10.0f, (float)(m + 1) * ms / 2595.0f) - 1.0f);
      float fp2 = 700.0f * (powf(10.0f, (float)(m + 2) * ms / 2595.0f) - 1.0f);
      float dn = (freq - fp0) / (fp1 - fp0);
      float up = (fp2 - freq) / (fp2 - fp1);
      v = fmaxf(0.0f, fminf(dn, up));
    }
    fbg[i] = f2bf(v);
  }
}

// One block = 128 frames of one batch row; 1024 threads = 16 waves (4/SIMD).
// GEMM1 waves: 4M x 4N — each wave 32 frames x 128 cols, acc[2][8].
// A (windowed frames, bf16) built ONCE into LDS (104 KB, all 13 ktiles).
// K-loop barrier-free: B fragments global->reg (chunk = base + lane*16).
// P = re^2+im^2 (bf16, LDS); GEMM2 swapped operands -> D[m][frame] direct store.
__global__ __launch_bounds__(1024) void k_gemm(const float* __restrict__ wav,
                                               const float* __restrict__ ws,
                                               float* __restrict__ mel) {
  extern __shared__ char sm[];  // A: [13 kt][8192 B]
  const char* Bg = (const char*)(ws + OFF_BG);
  const u16* FBg = (const u16*)(ws + OFF_FBG);  // [64 mel][264]
  const float* win = ws + OFF_WIN;
  int tid = threadIdx.x, wid = tid >> 6, lane = tid & 63;
  int wm = wid >> 2, wn = wid & 3;
  int bx = blockIdx.x, b = blockIdx.y;
  const float* wv = wav + (size_t)b * 160000;

  // ---- A build, all 13 ktiles: 8 lanes per frame row, 4 samples/lane ----
  {
    int kq8 = tid & 7, rowq = tid >> 3;          // rowq 0..127
    int khalf = kq8 >> 1, e4 = kq8 & 1;
    int frame = bx * 128 + rowq;
    bool fvalid = (frame <= 1000);
#pragma unroll 4
    for (int kt = 0; kt < 13; ++kt) {
      int n0 = kt * 32 + kq8 * 4;
      int g0 = frame * 160 + n0 - 200;
      float ax0, ax1, ax2, ax3;
      if (fvalid) {
        if (g0 >= 0 && g0 + 3 < 160000) {
          float4 u = *(const float4*)&wv[g0];
          ax0 = u.x; ax1 = u.y; ax2 = u.z; ax3 = u.w;
        } else {
          ax0 = wv[reflect_idx(g0)];
          ax1 = wv[reflect_idx(g0 + 1)];
          ax2 = wv[reflect_idx(g0 + 2)];
          ax3 = wv[reflect_idx(g0 + 3)];
        }
      } else {
        ax0 = ax1 = ax2 = ax3 = 0.0f;
      }
      float4 w = *(const float4*)&win[n0];
      uint2 pk;
      pk.x = (u32)f2bf(ax0 * w.x) | ((u32)f2bf(ax1 * w.y) << 16);
      pk.y = (u32)f2bf(ax2 * w.z) | ((u32)f2bf(ax3 * w.w) << 16);
      *(uint2*)(sm + kt * 8192 + khalf * 2048 + rowq * 16 + e4 * 8) = pk;
    }
  }
  __syncthreads();

  // ---- GEMM1: barrier-free K-loop; wave (wm,wn): rows wm*32+32, cols wn*128+128
  f32x4 acc[2][8];
  const f32x4 zf = {0.0f, 0.0f, 0.0f, 0.0f};
#pragma unroll
  for (int mi = 0; mi < 2; ++mi)
#pragma unroll
    for (int nf = 0; nf < 8; ++nf) acc[mi][nf] = zf;

#pragma unroll
  for (int kt = 0; kt < 13; ++kt) {
    bf16x8 bfr[8], af[2];
#pragma unroll
    for (int nf = 0; nf < 8; ++nf)
      bfr[nf] = *(const bf16x8*)(Bg + kt * 32768 + (wn * 8 + nf) * 1024 + lane * 16);
#pragma unroll
    for (int mi = 0; mi < 2; ++mi)
      af[mi] = *(const bf16x8*)(sm + kt * 8192 + (lane >> 4) * 2048 +
                                (wm * 32 + mi * 16 + (lane & 15)) * 16);
#pragma unroll
    for (int mi = 0; mi < 2; ++mi)
#pragma unroll
      for (int nf = 0; nf < 8; ++nf)
        acc[mi][nf] = __builtin_amdgcn_mfma_f32_16x16x32_bf16(af[mi], bfr[nf], acc[mi][nf], 0, 0, 0);
  }
  __syncthreads();  // all A reads done before P overwrites the region

  // ---- P = re^2+im^2 (bf16) @ LDS 0, stride 268 ----
  u16* P = (u16*)sm;  // [128 frame][268]
#pragma unroll
  for (int mi = 0; mi < 2; ++mi)
#pragma unroll
    for (int i = 0; i < 4; ++i)
#pragma unroll
      for (int r = 0; r < 4; ++r) {
        int row = wm * 32 + mi * 16 + (lane >> 4) * 4 + r;  // frame
        int bin = wn * 64 + i * 16 + (lane & 15);           // freq bin
        float re = acc[mi][2 * i][r], im = acc[mi][2 * i + 1][r];
        P[row * P_STRIDE + bin] = f2bf(re * re + im * im);
      }
  __syncthreads();

  // ---- GEMM2 (swapped): D[m][frame] = FB[m][bins] x P^T[bins][frame]
  // wave: frame group fg = wid&7 (16 frames), mel half mh = (wid>>3)*32.
  int fg = wid & 7, mh = (wid >> 3) * 32;
  f32x4 macc[2];
#pragma unroll
  for (int nf = 0; nf < 2; ++nf) macc[nf] = zf;
#pragma unroll
  for (int kt = 0; kt < 8; ++kt) {
    int krow = kt * 32 + (lane >> 4) * 8;
    bf16x8 pb = *(const bf16x8*)&P[(fg * 16 + (lane & 15)) * P_STRIDE + krow];
#pragma unroll
    for (int nf = 0; nf < 2; ++nf) {
      bf16x8 fa = *(const bf16x8*)&FBg[(mh + nf * 16 + (lane & 15)) * 264 + krow];
      macc[nf] = __builtin_amdgcn_mfma_f32_16x16x32_bf16(fa, pb, macc[nf], 0, 0, 0);
    }
  }

  // ---- direct store: col = frame, row = m ----
  int t = bx * 128 + fg * 16 + (lane & 15);
  if (t <= 1000) {
#pragma unroll
    for (int nf = 0; nf < 2; ++nf)
#pragma unroll
      for (int r = 0; r < 4; ++r) {
        int m = mh + nf * 16 + (lane >> 4) * 4 + r;
        mel[((size_t)b * 64 + m) * MEL_STRIDE + t] = macc[nf][r];
      }
  }
}

// Wave-parallel EMA scan: one wave per (b,m) row, 16 t/lane, affine map compose.
__global__ __launch_bounds__(256) void k_ema(const float* __restrict__ mel,
                                             float* __restrict__ outp) {
  int wid = threadIdx.x >> 6, lane = threadIdx.x & 63;
  int row = blockIdx.x * 4 + wid;  // 0..4095
  const float* src = mel + (size_t)row * MEL_STRIDE + lane * 16;

  float x[16];
  if (lane < 63) {
    float4 v0 = *(const float4*)&src[0];
    float4 v1 = *(const float4*)&src[4];
    float4 v2 = *(const float4*)&src[8];
    float4 v3 = *(const float4*)&src[12];
    x[0] = v0.x; x[1] = v0.y; x[2] = v0.z; x[3] = v0.w;
    x[4] = v1.x; x[5] = v1.y; x[6] = v1.z; x[7] = v1.w;
    x[8] = v2.x; x[9] = v2.y; x[10] = v2.z; x[11] = v2.w;
    x[12] = v3.x; x[13] = v3.y; x[14] = v3.z; x[15] = v3.w;
#pragma unroll
    for (int i = 0; i < 16; ++i)
      if (lane * 16 + i > 1000) x[i] = 0.0f;
  } else {
#pragma unroll
    for (int i = 0; i < 16; ++i) x[i] = 0.0f;
  }

  float B = 0.0f;
#pragma unroll
  for (int i = 0; i < 16; ++i) B = fmaf(0.98f, B, 0.02f * x[i]);
  float A = 1.0f;
#pragma unroll
  for (int i = 0; i < 16; ++i) A *= 0.98f;

#pragma unroll
  for (int d = 1; d < 64; d <<= 1) {
    float Ap = __shfl_up(A, d, 64);
    float Bp = __shfl_up(B, d, 64);
    if (lane >= d) {
      B = fmaf(A, Bp, B);
      A = A * Ap;
    }
  }
  float s = __shfl_up(B, 1, 64);
  if (lane == 0) s = 0.0f;

  float* dst = outp + (size_t)row * 1001 + lane * 16;
#pragma unroll
  for (int i = 0; i < 16; ++i) {
    s = fmaf(0.98f, s, 0.02f * x[i]);
    if (lane * 16 + i <= 1000) dst[i] = log1pf(x[i] / (s + 1e-6f));
  }
}

// mfcc[b][k][t] = sum_m 10*log10(max(mel,1e-10)) * DCT[m][k]
__global__ __launch_bounds__(256) void k_mfcc(const float* __restrict__ mel,
                                              const float* __restrict__ ws,
                                              float* __restrict__ outp) {
  __shared__ float dls[64 * 20];
  const float* dct = ws + OFF_DCT;
  for (int i = threadIdx.x; i < 64 * 20; i += 256) dls[i] = dct[i];
  __syncthreads();
  int b = blockIdx.y;
  int t = blockIdx.x * 256 + threadIdx.x;
  if (t >= T_FRAMES) return;
  float acc[20];
#pragma unroll
  for (int k = 0; k < 20; ++k) acc[k] = 0.0f;
  for (int m = 0; m < 64; ++m) {
    float v = mel[((size_t)b * 64 + m) * MEL_STRIDE + t];
    float db = 10.0f * log10f(fmaxf(v, 1e-10f));
#pragma unroll
    for (int k = 0; k < 20; ++k) acc[k] = fmaf(db, dls[m * 20 + k], acc[k]);
  }
  float* o = outp + (size_t)b * 20 * 1001 + t;
#pragma unroll
  for (int k = 0; k < 20; ++k) o[(size_t)k * 1001] = acc[k];
}

extern "C" void kernel_launch(void* const* d_in, const int* in_sizes, int n_in,
                              void* d_out, int out_size, void* d_ws, size_t ws_size,
                              hipStream_t stream) {
  const float* wav = (const float*)d_in[0];
  float* out = (float*)d_out;
  float* ws = (float*)d_ws;
  float* mel = ws + OFF_MEL;

  hipFuncSetAttribute(reinterpret_cast<const void*>(k_gemm),
                      hipFuncAttributeMaxDynamicSharedMemorySize, 106496);

  hipLaunchKernelGGL(k_init, dim3(64), dim3(256), 0, stream, ws);
  hipLaunchKernelGGL(k_gemm, dim3(8, 64), dim3(1024), 106496, stream, wav, ws, mel);
  hipLaunchKernelGGL(k_ema, dim3(1024), dim3(256), 0, stream, mel, out);
  hipLaunchKernelGGL(k_mfcc, dim3(4, 64), dim3(256), 0, stream, mel, ws, out + 4100096);
}

// Round 13
// 150.257 us; speedup vs baseline: 1.0012x; 1.0012x over previous
//
#include <hip/hip_runtime.h>

#define T_FRAMES 1001
#define MEL_STRIDE 1008
#define P_STRIDE 268

// ws float offsets
#define OFF_WIN 0          // [416] f32
#define OFF_DCT 416        // [64][20] f32
#define OFF_BG  1696       // u16[13 ktile][16384] twiddles, chunked (106496 f)
#define OFF_FBG 108192     // u16[64 mel][264] (8448 f)
#define OFF_MEL 13748128   // f32 [4096][1008]

typedef unsigned int u32;
typedef unsigned short u16;
typedef __attribute__((ext_vector_type(8))) short bf16x8;
typedef __attribute__((ext_vector_type(4))) float f32x4;

__device__ __forceinline__ u16 f2bf(float f) {
  u32 u = __float_as_uint(f);
  u32 r = (u + 0x7FFFu + ((u >> 16) & 1u)) >> 16;
  return (u16)r;
}

__device__ __forceinline__ int reflect_idx(int g) {
  g = (g < 0) ? -g : g;
  g = (g >= 160000) ? (319998 - g) : g;
  return g;
}

__global__ __launch_bounds__(256) void k_init(float* __restrict__ ws) {
  float* win = ws + OFF_WIN;
  float* dct = ws + OFF_DCT;
  u16* bg = (u16*)(ws + OFF_BG);
  u16* fbg = (u16*)(ws + OFF_FBG);
  const float W = 6.28318530717958647692f / 400.0f;
  int tid = blockIdx.x * 256 + threadIdx.x;
  int stride = gridDim.x * 256;
  for (int i = tid; i < 416; i += stride)
    win[i] = (i < 400) ? (0.5f - 0.5f * cosf((float)i * W)) : 0.0f;
  for (int i = tid; i < 64 * 20; i += stride) {
    int m = i / 20, k = i % 20;
    float v = cosf(3.14159265358979323846f / 64.0f * ((float)m + 0.5f) * (float)k) * sqrtf(2.0f / 64.0f);
    if (k == 0) v *= 0.70710678118654752440f;
    dct[i] = v;
  }
  // twiddles, chunked: u16 index = kt*16384 + g*512 + khalf*128 + c15*8 + e
  for (int i = tid; i < 13 * 16384; i += stride) {
    int kt = i >> 14;
    int r = i & 16383;
    int g = r >> 9;
    int khalf = (r >> 7) & 3;
    int c15 = (r >> 3) & 15;
    int e = r & 7;
    int col = g * 16 + c15;
    int n = kt * 32 + khalf * 8 + e;
    int bin = ((col >> 5) << 4) | (col & 15);
    int type = (col >> 4) & 1;
    float v = 0.0f;
    if (n < 400 && bin <= 200) {
      float a = (float)((n * bin) % 400) * W;
      v = type ? -sinf(a) : cosf(a);
    }
    bg[i] = f2bf(v);
  }
  // mel filterbank [mel][264], zero past bin 200
  for (int i = tid; i < 64 * 264; i += stride) {
    int m = i / 264, f = i % 264;
    float v = 0.0f;
    if (f <= 200) {
      float freq = 40.0f * (float)f;
      float m_max = 2595.0f * log10f(1.0f + 8000.0f / 700.0f);
      float ms = m_max / 65.0f;
      float fp0 = 700.0f * (powf(10.0f, (float)(m)     * ms / 2595.0f) - 1.0f);
      float fp1 = 700.0f * (powf(10.0f, (float)(m + 1) * ms / 2595.0f) - 1.0f);
      float fp2 = 700.0f * (powf(10.0f, (float)(m + 2) * ms / 2595.0f) - 1.0f);
      float dn = (freq - fp0) / (fp1 - fp0);
      float up = (fp2 - freq) / (fp2 - fp1);
      v = fmaxf(0.0f, fminf(dn, up));
    }
    fbg[i] = f2bf(v);
  }
}

// One block = 128 frames of one batch row; 1024 threads = 16 waves (4/SIMD).
// __launch_bounds__(1024, 4): 4 waves/EU -> 1 block/CU, VGPR cap 128 (r12's
// unhinted build capped at 64 and spilled ~113 MB to scratch).
// GEMM1 waves: 4M x 4N — each wave 32 frames x 128 cols, acc[2][8].
// A (windowed frames, bf16) built ONCE into LDS (104 KB, all 13 ktiles).
// K-loop barrier-free: B fragments global->reg (chunk = base + lane*16).
// P = re^2+im^2 (bf16, LDS); GEMM2 swapped operands -> D[m][frame] direct store.
__global__ __launch_bounds__(1024, 4) void k_gemm(const float* __restrict__ wav,
                                                  const float* __restrict__ ws,
                                                  float* __restrict__ mel) {
  extern __shared__ char sm[];  // A: [13 kt][8192 B]
  const char* Bg = (const char*)(ws + OFF_BG);
  const u16* FBg = (const u16*)(ws + OFF_FBG);  // [64 mel][264]
  const float* win = ws + OFF_WIN;
  int tid = threadIdx.x, wid = tid >> 6, lane = tid & 63;
  int wm = wid >> 2, wn = wid & 3;
  int bx = blockIdx.x, b = blockIdx.y;
  const float* wv = wav + (size_t)b * 160000;

  // ---- A build, all 13 ktiles: 8 lanes per frame row, 4 samples/lane ----
  {
    int kq8 = tid & 7, rowq = tid >> 3;          // rowq 0..127
    int khalf = kq8 >> 1, e4 = kq8 & 1;
    int frame = bx * 128 + rowq;
    bool fvalid = (frame <= 1000);
#pragma unroll 4
    for (int kt = 0; kt < 13; ++kt) {
      int n0 = kt * 32 + kq8 * 4;
      int g0 = frame * 160 + n0 - 200;
      float ax0, ax1, ax2, ax3;
      if (fvalid) {
        if (g0 >= 0 && g0 + 3 < 160000) {
          float4 u = *(const float4*)&wv[g0];
          ax0 = u.x; ax1 = u.y; ax2 = u.z; ax3 = u.w;
        } else {
          ax0 = wv[reflect_idx(g0)];
          ax1 = wv[reflect_idx(g0 + 1)];
          ax2 = wv[reflect_idx(g0 + 2)];
          ax3 = wv[reflect_idx(g0 + 3)];
        }
      } else {
        ax0 = ax1 = ax2 = ax3 = 0.0f;
      }
      float4 w = *(const float4*)&win[n0];
      uint2 pk;
      pk.x = (u32)f2bf(ax0 * w.x) | ((u32)f2bf(ax1 * w.y) << 16);
      pk.y = (u32)f2bf(ax2 * w.z) | ((u32)f2bf(ax3 * w.w) << 16);
      *(uint2*)(sm + kt * 8192 + khalf * 2048 + rowq * 16 + e4 * 8) = pk;
    }
  }
  __syncthreads();

  // ---- GEMM1: barrier-free K-loop; wave (wm,wn): rows wm*32+32, cols wn*128+128
  f32x4 acc[2][8];
  const f32x4 zf = {0.0f, 0.0f, 0.0f, 0.0f};
#pragma unroll
  for (int mi = 0; mi < 2; ++mi)
#pragma unroll
    for (int nf = 0; nf < 8; ++nf) acc[mi][nf] = zf;

#pragma unroll
  for (int kt = 0; kt < 13; ++kt) {
    bf16x8 bfr[8], af[2];
#pragma unroll
    for (int nf = 0; nf < 8; ++nf)
      bfr[nf] = *(const bf16x8*)(Bg + kt * 32768 + (wn * 8 + nf) * 1024 + lane * 16);
#pragma unroll
    for (int mi = 0; mi < 2; ++mi)
      af[mi] = *(const bf16x8*)(sm + kt * 8192 + (lane >> 4) * 2048 +
                                (wm * 32 + mi * 16 + (lane & 15)) * 16);
#pragma unroll
    for (int mi = 0; mi < 2; ++mi)
#pragma unroll
      for (int nf = 0; nf < 8; ++nf)
        acc[mi][nf] = __builtin_amdgcn_mfma_f32_16x16x32_bf16(af[mi], bfr[nf], acc[mi][nf], 0, 0, 0);
  }
  __syncthreads();  // all A reads done before P overwrites the region

  // ---- P = re^2+im^2 (bf16) @ LDS 0, stride 268 ----
  u16* P = (u16*)sm;  // [128 frame][268]
#pragma unroll
  for (int mi = 0; mi < 2; ++mi)
#pragma unroll
    for (int i = 0; i < 4; ++i)
#pragma unroll
      for (int r = 0; r < 4; ++r) {
        int row = wm * 32 + mi * 16 + (lane >> 4) * 4 + r;  // frame
        int bin = wn * 64 + i * 16 + (lane & 15);           // freq bin
        float re = acc[mi][2 * i][r], im = acc[mi][2 * i + 1][r];
        P[row * P_STRIDE + bin] = f2bf(re * re + im * im);
      }
  __syncthreads();

  // ---- GEMM2 (swapped): D[m][frame] = FB[m][bins] x P^T[bins][frame]
  // wave: frame group fg = wid&7 (16 frames), mel half mh = (wid>>3)*32.
  int fg = wid & 7, mh = (wid >> 3) * 32;
  f32x4 macc[2];
#pragma unroll
  for (int nf = 0; nf < 2; ++nf) macc[nf] = zf;
#pragma unroll
  for (int kt = 0; kt < 8; ++kt) {
    int krow = kt * 32 + (lane >> 4) * 8;
    bf16x8 pb = *(const bf16x8*)&P[(fg * 16 + (lane & 15)) * P_STRIDE + krow];
#pragma unroll
    for (int nf = 0; nf < 2; ++nf) {
      bf16x8 fa = *(const bf16x8*)&FBg[(mh + nf * 16 + (lane & 15)) * 264 + krow];
      macc[nf] = __builtin_amdgcn_mfma_f32_16x16x32_bf16(fa, pb, macc[nf], 0, 0, 0);
    }
  }

  // ---- direct store: col = frame, row = m ----
  int t = bx * 128 + fg * 16 + (lane & 15);
  if (t <= 1000) {
#pragma unroll
    for (int nf = 0; nf < 2; ++nf)
#pragma unroll
      for (int r = 0; r < 4; ++r) {
        int m = mh + nf * 16 + (lane >> 4) * 4 + r;
        mel[((size_t)b * 64 + m) * MEL_STRIDE + t] = macc[nf][r];
      }
  }
}

// Wave-parallel EMA scan: one wave per (b,m) row, 16 t/lane, affine map compose.
__global__ __launch_bounds__(256) void k_ema(const float* __restrict__ mel,
                                             float* __restrict__ outp) {
  int wid = threadIdx.x >> 6, lane = threadIdx.x & 63;
  int row = blockIdx.x * 4 + wid;  // 0..4095
  const float* src = mel + (size_t)row * MEL_STRIDE + lane * 16;

  float x[16];
  if (lane < 63) {
    float4 v0 = *(const float4*)&src[0];
    float4 v1 = *(const float4*)&src[4];
    float4 v2 = *(const float4*)&src[8];
    float4 v3 = *(const float4*)&src[12];
    x[0] = v0.x; x[1] = v0.y; x[2] = v0.z; x[3] = v0.w;
    x[4] = v1.x; x[5] = v1.y; x[6] = v1.z; x[7] = v1.w;
    x[8] = v2.x; x[9] = v2.y; x[10] = v2.z; x[11] = v2.w;
    x[12] = v3.x; x[13] = v3.y; x[14] = v3.z; x[15] = v3.w;
#pragma unroll
    for (int i = 0; i < 16; ++i)
      if (lane * 16 + i > 1000) x[i] = 0.0f;
  } else {
#pragma unroll
    for (int i = 0; i < 16; ++i) x[i] = 0.0f;
  }

  float B = 0.0f;
#pragma unroll
  for (int i = 0; i < 16; ++i) B = fmaf(0.98f, B, 0.02f * x[i]);
  float A = 1.0f;
#pragma unroll
  for (int i = 0; i < 16; ++i) A *= 0.98f;

#pragma unroll
  for (int d = 1; d < 64; d <<= 1) {
    float Ap = __shfl_up(A, d, 64);
    float Bp = __shfl_up(B, d, 64);
    if (lane >= d) {
      B = fmaf(A, Bp, B);
      A = A * Ap;
    }
  }
  float s = __shfl_up(B, 1, 64);
  if (lane == 0) s = 0.0f;

  float* dst = outp + (size_t)row * 1001 + lane * 16;
#pragma unroll
  for (int i = 0; i < 16; ++i) {
    s = fmaf(0.98f, s, 0.02f * x[i]);
    if (lane * 16 + i <= 1000) dst[i] = log1pf(x[i] / (s + 1e-6f));
  }
}

// mfcc[b][k][t] = sum_m 10*log10(max(mel,1e-10)) * DCT[m][k]
__global__ __launch_bounds__(256) void k_mfcc(const float* __restrict__ mel,
                                              const float* __restrict__ ws,
                                              float* __restrict__ outp) {
  __shared__ float dls[64 * 20];
  const float* dct = ws + OFF_DCT;
  for (int i = threadIdx.x; i < 64 * 20; i += 256) dls[i] = dct[i];
  __syncthreads();
  int b = blockIdx.y;
  int t = blockIdx.x * 256 + threadIdx.x;
  if (t >= T_FRAMES) return;
  float acc[20];
#pragma unroll
  for (int k = 0; k < 20; ++k) acc[k] = 0.0f;
  for (int m = 0; m < 64; ++m) {
    float v = mel[((size_t)b * 64 + m) * MEL_STRIDE + t];
    float db = 10.0f * log10f(fmaxf(v, 1e-10f));
#pragma unroll
    for (int k = 0; k < 20; ++k) acc[k] = fmaf(db, dls[m * 20 + k], acc[k]);
  }
  float* o = outp + (size_t)b * 20 * 1001 + t;
#pragma unroll
  for (int k = 0; k < 20; ++k) o[(size_t)k * 1001] = acc[k];
}

extern "C" void kernel_launch(void* const* d_in, const int* in_sizes, int n_in,
                              void* d_out, int out_size, void* d_ws, size_t ws_size,
                              hipStream_t stream) {
  const float* wav = (const float*)d_in[0];
  float* out = (float*)d_out;
  float* ws = (float*)d_ws;
  float* mel = ws + OFF_MEL;

  hipFuncSetAttribute(reinterpret_cast<const void*>(k_gemm),
                      hipFuncAttributeMaxDynamicSharedMemorySize, 106496);

  hipLaunchKernelGGL(k_init, dim3(64), dim3(256), 0, stream, ws);
  hipLaunchKernelGGL(k_gemm, dim3(8, 64), dim3(1024), 106496, stream, wav, ws, mel);
  hipLaunchKernelGGL(k_ema, dim3(1024), dim3(256), 0, stream, mel, out);
  hipLaunchKernelGGL(k_mfcc, dim3(4, 64), dim3(256), 0, stream, mel, ws, out + 4100096);
}

// Round 14
// 116.670 us; speedup vs baseline: 1.2894x; 1.2879x over previous
//
#include <hip/hip_runtime.h>

#define T_FRAMES 1001
#define MEL_STRIDE 1008
#define P_STRIDE 268

// ws float offsets
#define OFF_WIN 0          // [416] f32
#define OFF_DCT 416        // [64][20] f32
#define OFF_BG  1696       // u16[13 ktile][16384] twiddles, chunked (106496 f)
#define OFF_FBG 108192     // u16[64 mel][264] (8448 f)
#define OFF_MEL 13748128   // f32 [4096][1008]

typedef unsigned int u32;
typedef unsigned short u16;
typedef __attribute__((ext_vector_type(8))) short bf16x8;
typedef __attribute__((ext_vector_type(4))) float f32x4;

__device__ __forceinline__ u16 f2bf(float f) {
  u32 u = __float_as_uint(f);
  u32 r = (u + 0x7FFFu + ((u >> 16) & 1u)) >> 16;
  return (u16)r;
}

__device__ __forceinline__ int reflect_idx(int g) {
  g = (g < 0) ? -g : g;
  g = (g >= 160000) ? (319998 - g) : g;
  return g;
}

__global__ __launch_bounds__(256) void k_init(float* __restrict__ ws) {
  float* win = ws + OFF_WIN;
  float* dct = ws + OFF_DCT;
  u16* bg = (u16*)(ws + OFF_BG);
  u16* fbg = (u16*)(ws + OFF_FBG);
  const float W = 6.28318530717958647692f / 400.0f;
  int tid = blockIdx.x * 256 + threadIdx.x;
  int stride = gridDim.x * 256;
  for (int i = tid; i < 416; i += stride)
    win[i] = (i < 400) ? (0.5f - 0.5f * cosf((float)i * W)) : 0.0f;
  for (int i = tid; i < 64 * 20; i += stride) {
    int m = i / 20, k = i % 20;
    float v = cosf(3.14159265358979323846f / 64.0f * ((float)m + 0.5f) * (float)k) * sqrtf(2.0f / 64.0f);
    if (k == 0) v *= 0.70710678118654752440f;
    dct[i] = v;
  }
  // twiddles, chunked: u16 index = kt*16384 + g*512 + khalf*128 + c15*8 + e
  for (int i = tid; i < 13 * 16384; i += stride) {
    int kt = i >> 14;
    int r = i & 16383;
    int g = r >> 9;
    int khalf = (r >> 7) & 3;
    int c15 = (r >> 3) & 15;
    int e = r & 7;
    int col = g * 16 + c15;
    int n = kt * 32 + khalf * 8 + e;
    int bin = ((col >> 5) << 4) | (col & 15);
    int type = (col >> 4) & 1;
    float v = 0.0f;
    if (n < 400 && bin <= 200) {
      float a = (float)((n * bin) % 400) * W;
      v = type ? -sinf(a) : cosf(a);
    }
    bg[i] = f2bf(v);
  }
  // mel filterbank [mel][264], zero past bin 200
  for (int i = tid; i < 64 * 264; i += stride) {
    int m = i / 264, f = i % 264;
    float v = 0.0f;
    if (f <= 200) {
      float freq = 40.0f * (float)f;
      float m_max = 2595.0f * log10f(1.0f + 8000.0f / 700.0f);
      float ms = m_max / 65.0f;
      float fp0 = 700.0f * (powf(10.0f, (float)(m)     * ms / 2595.0f) - 1.0f);
      float fp1 = 700.0f * (powf(10.0f, (float)(m + 1) * ms / 2595.0f) - 1.0f);
      float fp2 = 700.0f * (powf(10.0f, (float)(m + 2) * ms / 2595.0f) - 1.0f);
      float dn = (freq - fp0) / (fp1 - fp0);
      float up = (fp2 - freq) / (fp2 - fp1);
      v = fmaxf(0.0f, fminf(dn, up));
    }
    fbg[i] = f2bf(v);
  }
}

// One block = 128 frames of one batch row; 1024 threads = 16 waves (4/SIMD).
// __launch_bounds__(1024, 1): empirically the 2nd arg acts as min BLOCKS/CU
// (r13's (1024,4) clamped VGPR to 64 and spilled ~115 MB) -> 1 block/CU, cap 128.
// GEMM1 waves: 4M x 4N — wave = 32 frames x 128 cols, acc[2][8] (64 AGPR).
// Inner loop holds ONE bfr at a time (2 MFMAs per load) to fit the 128-reg cap.
// A (windowed frames, bf16) built ONCE into LDS (104 KB, all 13 ktiles).
// P = re^2+im^2 (bf16, LDS); GEMM2 swapped operands -> D[m][frame] direct store.
__global__ __launch_bounds__(1024, 1) void k_gemm(const float* __restrict__ wav,
                                                  const float* __restrict__ ws,
                                                  float* __restrict__ mel) {
  extern __shared__ char sm[];  // A: [13 kt][8192 B]
  const char* Bg = (const char*)(ws + OFF_BG);
  const u16* FBg = (const u16*)(ws + OFF_FBG);  // [64 mel][264]
  const float* win = ws + OFF_WIN;
  int tid = threadIdx.x, wid = tid >> 6, lane = tid & 63;
  int wm = wid >> 2, wn = wid & 3;
  int bx = blockIdx.x, b = blockIdx.y;
  const float* wv = wav + (size_t)b * 160000;

  // ---- A build, all 13 ktiles: 8 lanes per frame row, 4 samples/lane ----
  {
    int kq8 = tid & 7, rowq = tid >> 3;          // rowq 0..127
    int khalf = kq8 >> 1, e4 = kq8 & 1;
    int frame = bx * 128 + rowq;
    bool fvalid = (frame <= 1000);
#pragma unroll 4
    for (int kt = 0; kt < 13; ++kt) {
      int n0 = kt * 32 + kq8 * 4;
      int g0 = frame * 160 + n0 - 200;
      float ax0, ax1, ax2, ax3;
      if (fvalid) {
        if (g0 >= 0 && g0 + 3 < 160000) {
          float4 u = *(const float4*)&wv[g0];
          ax0 = u.x; ax1 = u.y; ax2 = u.z; ax3 = u.w;
        } else {
          ax0 = wv[reflect_idx(g0)];
          ax1 = wv[reflect_idx(g0 + 1)];
          ax2 = wv[reflect_idx(g0 + 2)];
          ax3 = wv[reflect_idx(g0 + 3)];
        }
      } else {
        ax0 = ax1 = ax2 = ax3 = 0.0f;
      }
      float4 w = *(const float4*)&win[n0];
      uint2 pk;
      pk.x = (u32)f2bf(ax0 * w.x) | ((u32)f2bf(ax1 * w.y) << 16);
      pk.y = (u32)f2bf(ax2 * w.z) | ((u32)f2bf(ax3 * w.w) << 16);
      *(uint2*)(sm + kt * 8192 + khalf * 2048 + rowq * 16 + e4 * 8) = pk;
    }
  }
  __syncthreads();

  // ---- GEMM1: barrier-free K-loop; wave (wm,wn): rows wm*32+32, cols wn*128+128
  f32x4 acc[2][8];
  const f32x4 zf = {0.0f, 0.0f, 0.0f, 0.0f};
#pragma unroll
  for (int mi = 0; mi < 2; ++mi)
#pragma unroll
    for (int nf = 0; nf < 8; ++nf) acc[mi][nf] = zf;

#pragma unroll
  for (int kt = 0; kt < 13; ++kt) {
    bf16x8 af[2];
#pragma unroll
    for (int mi = 0; mi < 2; ++mi)
      af[mi] = *(const bf16x8*)(sm + kt * 8192 + (lane >> 4) * 2048 +
                                (wm * 32 + mi * 16 + (lane & 15)) * 16);
#pragma unroll
    for (int nf = 0; nf < 8; ++nf) {
      bf16x8 bfr = *(const bf16x8*)(Bg + kt * 32768 + (wn * 8 + nf) * 1024 + lane * 16);
      acc[0][nf] = __builtin_amdgcn_mfma_f32_16x16x32_bf16(af[0], bfr, acc[0][nf], 0, 0, 0);
      acc[1][nf] = __builtin_amdgcn_mfma_f32_16x16x32_bf16(af[1], bfr, acc[1][nf], 0, 0, 0);
    }
  }
  __syncthreads();  // all A reads done before P overwrites the region

  // ---- P = re^2+im^2 (bf16) @ LDS 0, stride 268 ----
  u16* P = (u16*)sm;  // [128 frame][268]
#pragma unroll
  for (int mi = 0; mi < 2; ++mi)
#pragma unroll
    for (int i = 0; i < 4; ++i)
#pragma unroll
      for (int r = 0; r < 4; ++r) {
        int row = wm * 32 + mi * 16 + (lane >> 4) * 4 + r;  // frame
        int bin = wn * 64 + i * 16 + (lane & 15);           // freq bin
        float re = acc[mi][2 * i][r], im = acc[mi][2 * i + 1][r];
        P[row * P_STRIDE + bin] = f2bf(re * re + im * im);
      }
  __syncthreads();

  // ---- GEMM2 (swapped): D[m][frame] = FB[m][bins] x P^T[bins][frame]
  // wave: frame group fg = wid&7 (16 frames), mel half mh = (wid>>3)*32.
  int fg = wid & 7, mh = (wid >> 3) * 32;
  f32x4 macc[2];
#pragma unroll
  for (int nf = 0; nf < 2; ++nf) macc[nf] = zf;
#pragma unroll
  for (int kt = 0; kt < 8; ++kt) {
    int krow = kt * 32 + (lane >> 4) * 8;
    bf16x8 pb = *(const bf16x8*)&P[(fg * 16 + (lane & 15)) * P_STRIDE + krow];
#pragma unroll
    for (int nf = 0; nf < 2; ++nf) {
      bf16x8 fa = *(const bf16x8*)&FBg[(mh + nf * 16 + (lane & 15)) * 264 + krow];
      macc[nf] = __builtin_amdgcn_mfma_f32_16x16x32_bf16(fa, pb, macc[nf], 0, 0, 0);
    }
  }

  // ---- direct store: col = frame, row = m ----
  int t = bx * 128 + fg * 16 + (lane & 15);
  if (t <= 1000) {
#pragma unroll
    for (int nf = 0; nf < 2; ++nf)
#pragma unroll
      for (int r = 0; r < 4; ++r) {
        int m = mh + nf * 16 + (lane >> 4) * 4 + r;
        mel[((size_t)b * 64 + m) * MEL_STRIDE + t] = macc[nf][r];
      }
  }
}

// Wave-parallel EMA scan: one wave per (b,m) row, 16 t/lane, affine map compose.
__global__ __launch_bounds__(256) void k_ema(const float* __restrict__ mel,
                                             float* __restrict__ outp) {
  int wid = threadIdx.x >> 6, lane = threadIdx.x & 63;
  int row = blockIdx.x * 4 + wid;  // 0..4095
  const float* src = mel + (size_t)row * MEL_STRIDE + lane * 16;

  float x[16];
  if (lane < 63) {
    float4 v0 = *(const float4*)&src[0];
    float4 v1 = *(const float4*)&src[4];
    float4 v2 = *(const float4*)&src[8];
    float4 v3 = *(const float4*)&src[12];
    x[0] = v0.x; x[1] = v0.y; x[2] = v0.z; x[3] = v0.w;
    x[4] = v1.x; x[5] = v1.y; x[6] = v1.z; x[7] = v1.w;
    x[8] = v2.x; x[9] = v2.y; x[10] = v2.z; x[11] = v2.w;
    x[12] = v3.x; x[13] = v3.y; x[14] = v3.z; x[15] = v3.w;
#pragma unroll
    for (int i = 0; i < 16; ++i)
      if (lane * 16 + i > 1000) x[i] = 0.0f;
  } else {
#pragma unroll
    for (int i = 0; i < 16; ++i) x[i] = 0.0f;
  }

  float B = 0.0f;
#pragma unroll
  for (int i = 0; i < 16; ++i) B = fmaf(0.98f, B, 0.02f * x[i]);
  float A = 1.0f;
#pragma unroll
  for (int i = 0; i < 16; ++i) A *= 0.98f;

#pragma unroll
  for (int d = 1; d < 64; d <<= 1) {
    float Ap = __shfl_up(A, d, 64);
    float Bp = __shfl_up(B, d, 64);
    if (lane >= d) {
      B = fmaf(A, Bp, B);
      A = A * Ap;
    }
  }
  float s = __shfl_up(B, 1, 64);
  if (lane == 0) s = 0.0f;

  float* dst = outp + (size_t)row * 1001 + lane * 16;
#pragma unroll
  for (int i = 0; i < 16; ++i) {
    s = fmaf(0.98f, s, 0.02f * x[i]);
    if (lane * 16 + i <= 1000) dst[i] = log1pf(x[i] / (s + 1e-6f));
  }
}

// mfcc[b][k][t] = sum_m 10*log10(max(mel,1e-10)) * DCT[m][k]
__global__ __launch_bounds__(256) void k_mfcc(const float* __restrict__ mel,
                                              const float* __restrict__ ws,
                                              float* __restrict__ outp) {
  __shared__ float dls[64 * 20];
  const float* dct = ws + OFF_DCT;
  for (int i = threadIdx.x; i < 64 * 20; i += 256) dls[i] = dct[i];
  __syncthreads();
  int b = blockIdx.y;
  int t = blockIdx.x * 256 + threadIdx.x;
  if (t >= T_FRAMES) return;
  float acc[20];
#pragma unroll
  for (int k = 0; k < 20; ++k) acc[k] = 0.0f;
  for (int m = 0; m < 64; ++m) {
    float v = mel[((size_t)b * 64 + m) * MEL_STRIDE + t];
    float db = 10.0f * log10f(fmaxf(v, 1e-10f));
#pragma unroll
    for (int k = 0; k < 20; ++k) acc[k] = fmaf(db, dls[m * 20 + k], acc[k]);
  }
  float* o = outp + (size_t)b * 20 * 1001 + t;
#pragma unroll
  for (int k = 0; k < 20; ++k) o[(size_t)k * 1001] = acc[k];
}

extern "C" void kernel_launch(void* const* d_in, const int* in_sizes, int n_in,
                              void* d_out, int out_size, void* d_ws, size_t ws_size,
                              hipStream_t stream) {
  const float* wav = (const float*)d_in[0];
  float* out = (float*)d_out;
  float* ws = (float*)d_ws;
  float* mel = ws + OFF_MEL;

  hipFuncSetAttribute(reinterpret_cast<const void*>(k_gemm),
                      hipFuncAttributeMaxDynamicSharedMemorySize, 106496);

  hipLaunchKernelGGL(k_init, dim3(64), dim3(256), 0, stream, ws);
  hipLaunchKernelGGL(k_gemm, dim3(8, 64), dim3(1024), 106496, stream, wav, ws, mel);
  hipLaunchKernelGGL(k_ema, dim3(1024), dim3(256), 0, stream, mel, out);
  hipLaunchKernelGGL(k_mfcc, dim3(4, 64), dim3(256), 0, stream, mel, ws, out + 4100096);
}

// Round 15
// 101.425 us; speedup vs baseline: 1.4832x; 1.1503x over previous
//
#include <hip/hip_runtime.h>

#define T_FRAMES 1001
#define MEL_STRIDE 1008
#define P_STRIDE 268

// ws float offsets
#define OFF_WIN 0          // [416] f32
#define OFF_DCT 416        // [64][20] f32
#define OFF_BG  1696       // u16[13 ktile][16384] twiddles, chunked (106496 f)
#define OFF_FBG 108192     // u16[64 mel][264] (8448 f)
#define OFF_MEL 13748128   // f32 [4096][1008]

typedef unsigned int u32;
typedef unsigned short u16;
typedef __attribute__((ext_vector_type(8))) short bf16x8;
typedef __attribute__((ext_vector_type(4))) float f32x4;

__device__ __forceinline__ u16 f2bf(float f) {
  u32 u = __float_as_uint(f);
  u32 r = (u + 0x7FFFu + ((u >> 16) & 1u)) >> 16;
  return (u16)r;
}

__device__ __forceinline__ int reflect_idx(int g) {
  g = (g < 0) ? -g : g;
  g = (g >= 160000) ? (319998 - g) : g;
  return g;
}

__global__ __launch_bounds__(256) void k_init(float* __restrict__ ws) {
  float* win = ws + OFF_WIN;
  float* dct = ws + OFF_DCT;
  u16* bg = (u16*)(ws + OFF_BG);
  u16* fbg = (u16*)(ws + OFF_FBG);
  const float W = 6.28318530717958647692f / 400.0f;
  int tid = blockIdx.x * 256 + threadIdx.x;
  int stride = gridDim.x * 256;
  for (int i = tid; i < 416; i += stride)
    win[i] = (i < 400) ? (0.5f - 0.5f * cosf((float)i * W)) : 0.0f;
  for (int i = tid; i < 64 * 20; i += stride) {
    int m = i / 20, k = i % 20;
    float v = cosf(3.14159265358979323846f / 64.0f * ((float)m + 0.5f) * (float)k) * sqrtf(2.0f / 64.0f);
    if (k == 0) v *= 0.70710678118654752440f;
    dct[i] = v;
  }
  // twiddles, chunked: u16 index = kt*16384 + g*512 + khalf*128 + c15*8 + e
  for (int i = tid; i < 13 * 16384; i += stride) {
    int kt = i >> 14;
    int r = i & 16383;
    int g = r >> 9;
    int khalf = (r >> 7) & 3;
    int c15 = (r >> 3) & 15;
    int e = r & 7;
    int col = g * 16 + c15;
    int n = kt * 32 + khalf * 8 + e;
    int bin = ((col >> 5) << 4) | (col & 15);
    int type = (col >> 4) & 1;
    float v = 0.0f;
    if (n < 400 && bin <= 200) {
      float a = (float)((n * bin) % 400) * W;
      v = type ? -sinf(a) : cosf(a);
    }
    bg[i] = f2bf(v);
  }
  // mel filterbank [mel][264], zero past bin 200
  for (int i = tid; i < 64 * 264; i += stride) {
    int m = i / 264, f = i % 264;
    float v = 0.0f;
    if (f <= 200) {
      float freq = 40.0f * (float)f;
      float m_max = 2595.0f * log10f(1.0f + 8000.0f / 700.0f);
      float ms = m_max / 65.0f;
      float fp0 = 700.0f * (powf(10.0f, (float)(m)     * ms / 2595.0f) - 1.0f);
      float fp1 = 700.0f * (powf(10.0f, (float)(m + 1) * ms / 2595.0f) - 1.0f);
      float fp2 = 700.0f * (powf(10.0f, (float)(m + 2) * ms / 2595.0f) - 1.0f);
      float dn = (freq - fp0) / (fp1 - fp0);
      float up = (fp2 - freq) / (fp2 - fp1);
      v = fmaxf(0.0f, fminf(dn, up));
    }
    fbg[i] = f2bf(v);
  }
}

// One block = 128 frames of one batch row; 512 threads = 8 waves (2M x 4N).
// NOTE: 1024-thread blocks are structurally reg-capped at 128/wave (16 waves
// must co-reside at 4/SIMD) -> r12-r14 spilled. 512 threads + (512,2) gives
// 256 regs/wave (128 AGPR acc + ~110 arch VGPR), zero spill (r11-verified).
// GEMM1: wave = 64 frames x 128 cols, acc[4][8]. B fragments global->reg with
// EXPLICIT double-buffer (bA/bB, prefetch kt+1 issued before kt's 32 MFMAs)
// so the ~250cyc L2 latency hides under MFMA issue (ILP; LDS size forbids TLP).
// A (windowed frames) built once into LDS (104 KB, all 13 ktiles).
// P = re^2+im^2 (bf16, LDS); GEMM2 swapped operands -> D[m][frame] direct store.
__global__ __launch_bounds__(512, 2) void k_gemm(const float* __restrict__ wav,
                                                 const float* __restrict__ ws,
                                                 float* __restrict__ mel) {
  extern __shared__ char sm[];  // A: [13 kt][8192 B]
  const char* Bg = (const char*)(ws + OFF_BG);
  const u16* FBg = (const u16*)(ws + OFF_FBG);  // [64 mel][264]
  const float* win = ws + OFF_WIN;
  int tid = threadIdx.x, wid = tid >> 6, lane = tid & 63;
  int wm = wid >> 2, wn = wid & 3;
  int bx = blockIdx.x, b = blockIdx.y;
  const float* wv = wav + (size_t)b * 160000;

  // ---- A build, all 13 ktiles: 4 lanes per frame row (coalesced reads) ----
  {
    int kq = tid & 3, rowq = tid >> 2;
    int frame = bx * 128 + rowq;
    bool fvalid = (frame <= 1000);
#pragma unroll 4
    for (int kt = 0; kt < 13; ++kt) {
      int n0 = kt * 32 + kq * 8;
      int g0 = frame * 160 + n0 - 200;
      float ax[8];
      if (fvalid) {
        if (g0 >= 0 && g0 + 7 < 160000) {
          float4 u = *(const float4*)&wv[g0];
          float4 v = *(const float4*)&wv[g0 + 4];
          ax[0] = u.x; ax[1] = u.y; ax[2] = u.z; ax[3] = u.w;
          ax[4] = v.x; ax[5] = v.y; ax[6] = v.z; ax[7] = v.w;
        } else {
#pragma unroll
          for (int e = 0; e < 8; ++e) ax[e] = wv[reflect_idx(g0 + e)];
        }
      } else {
#pragma unroll
        for (int e = 0; e < 8; ++e) ax[e] = 0.0f;
      }
      float4 w0 = *(const float4*)&win[n0];
      float4 w1 = *(const float4*)&win[n0 + 4];
      uint4 pk;
      pk.x = (u32)f2bf(ax[0] * w0.x) | ((u32)f2bf(ax[1] * w0.y) << 16);
      pk.y = (u32)f2bf(ax[2] * w0.z) | ((u32)f2bf(ax[3] * w0.w) << 16);
      pk.z = (u32)f2bf(ax[4] * w1.x) | ((u32)f2bf(ax[5] * w1.y) << 16);
      pk.w = (u32)f2bf(ax[6] * w1.z) | ((u32)f2bf(ax[7] * w1.w) << 16);
      *(uint4*)(sm + kt * 8192 + kq * 2048 + rowq * 16) = pk;
    }
  }
  __syncthreads();

  // ---- GEMM1: barrier-free K-loop with register-double-buffered B ----
  f32x4 acc[4][8];
  const f32x4 zf = {0.0f, 0.0f, 0.0f, 0.0f};
#pragma unroll
  for (int mi = 0; mi < 4; ++mi)
#pragma unroll
    for (int nf = 0; nf < 8; ++nf) acc[mi][nf] = zf;

  const char* Bw = Bg + wn * 8192 + lane * 16;  // + kt*32768 + nf*1024

#define LOAD_B(buf, ktc)                                          \
  _Pragma("unroll")                                               \
  for (int nf = 0; nf < 8; ++nf)                                  \
    buf[nf] = *(const bf16x8*)(Bw + (ktc) * 32768 + nf * 1024);

#define LOAD_AF(ktc)                                              \
  _Pragma("unroll")                                               \
  for (int mi = 0; mi < 4; ++mi)                                  \
    af[mi] = *(const bf16x8*)(sm + (ktc) * 8192 + (lane >> 4) * 2048 + \
                              (wm * 64 + mi * 16 + (lane & 15)) * 16);

#define MFMA_TILE(buf)                                            \
  _Pragma("unroll")                                               \
  for (int mi = 0; mi < 4; ++mi)                                  \
    _Pragma("unroll")                                             \
    for (int nf = 0; nf < 8; ++nf)                                \
      acc[mi][nf] = __builtin_amdgcn_mfma_f32_16x16x32_bf16(af[mi], buf[nf], acc[mi][nf], 0, 0, 0);

  bf16x8 bA[8], bB[8], af[4];
  LOAD_B(bA, 0);
#pragma unroll
  for (int kt2 = 0; kt2 < 13; kt2 += 2) {
    // even ktile kt2: consume bA; prefetch bB <- kt2+1
    if (kt2 + 1 < 13) { LOAD_B(bB, kt2 + 1); }
    LOAD_AF(kt2);
    MFMA_TILE(bA);
    // odd ktile kt2+1: consume bB; prefetch bA <- kt2+2
    if (kt2 + 1 < 13) {
      if (kt2 + 2 < 13) { LOAD_B(bA, kt2 + 2); }
      LOAD_AF(kt2 + 1);
      MFMA_TILE(bB);
    }
  }
  __syncthreads();  // all A reads done before P overwrites the region

  // ---- P = re^2+im^2 (bf16) @ LDS 0, stride 268 ----
  u16* P = (u16*)sm;  // [128 frame][268]
#pragma unroll
  for (int mi = 0; mi < 4; ++mi)
#pragma unroll
    for (int i = 0; i < 4; ++i)
#pragma unroll
      for (int r = 0; r < 4; ++r) {
        int row = wm * 64 + mi * 16 + (lane >> 4) * 4 + r;  // frame
        int bin = wn * 64 + i * 16 + (lane & 15);           // freq bin
        float re = acc[mi][2 * i][r], im = acc[mi][2 * i + 1][r];
        P[row * P_STRIDE + bin] = f2bf(re * re + im * im);
      }
  __syncthreads();

  // ---- GEMM2 (swapped): D[m][frame] = FB[m][bins] x P^T[bins][frame]
  // wave wid owns frames [wid*16, wid*16+16); nf = mel group.
  f32x4 macc[4];
#pragma unroll
  for (int nf = 0; nf < 4; ++nf) macc[nf] = zf;
#pragma unroll
  for (int kt = 0; kt < 8; ++kt) {
    int krow = kt * 32 + (lane >> 4) * 8;
    bf16x8 pb = *(const bf16x8*)&P[(wid * 16 + (lane & 15)) * P_STRIDE + krow];
#pragma unroll
    for (int nf = 0; nf < 4; ++nf) {
      bf16x8 fa = *(const bf16x8*)&FBg[(nf * 16 + (lane & 15)) * 264 + krow];
      macc[nf] = __builtin_amdgcn_mfma_f32_16x16x32_bf16(fa, pb, macc[nf], 0, 0, 0);
    }
  }

  // ---- direct store: D col = frame, row = m ----
  int t = bx * 128 + wid * 16 + (lane & 15);
  if (t <= 1000) {
#pragma unroll
    for (int nf = 0; nf < 4; ++nf)
#pragma unroll
      for (int r = 0; r < 4; ++r) {
        int m = nf * 16 + (lane >> 4) * 4 + r;
        mel[((size_t)b * 64 + m) * MEL_STRIDE + t] = macc[nf][r];
      }
  }
}

// Wave-parallel EMA scan: one wave per (b,m) row, 16 t/lane, affine map compose.
__global__ __launch_bounds__(256) void k_ema(const float* __restrict__ mel,
                                             float* __restrict__ outp) {
  int wid = threadIdx.x >> 6, lane = threadIdx.x & 63;
  int row = blockIdx.x * 4 + wid;  // 0..4095
  const float* src = mel + (size_t)row * MEL_STRIDE + lane * 16;

  float x[16];
  if (lane < 63) {
    float4 v0 = *(const float4*)&src[0];
    float4 v1 = *(const float4*)&src[4];
    float4 v2 = *(const float4*)&src[8];
    float4 v3 = *(const float4*)&src[12];
    x[0] = v0.x; x[1] = v0.y; x[2] = v0.z; x[3] = v0.w;
    x[4] = v1.x; x[5] = v1.y; x[6] = v1.z; x[7] = v1.w;
    x[8] = v2.x; x[9] = v2.y; x[10] = v2.z; x[11] = v2.w;
    x[12] = v3.x; x[13] = v3.y; x[14] = v3.z; x[15] = v3.w;
#pragma unroll
    for (int i = 0; i < 16; ++i)
      if (lane * 16 + i > 1000) x[i] = 0.0f;
  } else {
#pragma unroll
    for (int i = 0; i < 16; ++i) x[i] = 0.0f;
  }

  float B = 0.0f;
#pragma unroll
  for (int i = 0; i < 16; ++i) B = fmaf(0.98f, B, 0.02f * x[i]);
  float A = 1.0f;
#pragma unroll
  for (int i = 0; i < 16; ++i) A *= 0.98f;

#pragma unroll
  for (int d = 1; d < 64; d <<= 1) {
    float Ap = __shfl_up(A, d, 64);
    float Bp = __shfl_up(B, d, 64);
    if (lane >= d) {
      B = fmaf(A, Bp, B);
      A = A * Ap;
    }
  }
  float s = __shfl_up(B, 1, 64);
  if (lane == 0) s = 0.0f;

  float* dst = outp + (size_t)row * 1001 + lane * 16;
#pragma unroll
  for (int i = 0; i < 16; ++i) {
    s = fmaf(0.98f, s, 0.02f * x[i]);
    if (lane * 16 + i <= 1000) dst[i] = log1pf(x[i] / (s + 1e-6f));
  }
}

// mfcc[b][k][t] = sum_m 10*log10(max(mel,1e-10)) * DCT[m][k]
__global__ __launch_bounds__(256) void k_mfcc(const float* __restrict__ mel,
                                              const float* __restrict__ ws,
                                              float* __restrict__ outp) {
  __shared__ float dls[64 * 20];
  const float* dct = ws + OFF_DCT;
  for (int i = threadIdx.x; i < 64 * 20; i += 256) dls[i] = dct[i];
  __syncthreads();
  int b = blockIdx.y;
  int t = blockIdx.x * 256 + threadIdx.x;
  if (t >= T_FRAMES) return;
  float acc[20];
#pragma unroll
  for (int k = 0; k < 20; ++k) acc[k] = 0.0f;
  for (int m = 0; m < 64; ++m) {
    float v = mel[((size_t)b * 64 + m) * MEL_STRIDE + t];
    float db = 10.0f * log10f(fmaxf(v, 1e-10f));
#pragma unroll
    for (int k = 0; k < 20; ++k) acc[k] = fmaf(db, dls[m * 20 + k], acc[k]);
  }
  float* o = outp + (size_t)b * 20 * 1001 + t;
#pragma unroll
  for (int k = 0; k < 20; ++k) o[(size_t)k * 1001] = acc[k];
}

extern "C" void kernel_launch(void* const* d_in, const int* in_sizes, int n_in,
                              void* d_out, int out_size, void* d_ws, size_t ws_size,
                              hipStream_t stream) {
  const float* wav = (const float*)d_in[0];
  float* out = (float*)d_out;
  float* ws = (float*)d_ws;
  float* mel = ws + OFF_MEL;

  hipFuncSetAttribute(reinterpret_cast<const void*>(k_gemm),
                      hipFuncAttributeMaxDynamicSharedMemorySize, 106496);

  hipLaunchKernelGGL(k_init, dim3(64), dim3(256), 0, stream, ws);
  hipLaunchKernelGGL(k_gemm, dim3(8, 64), dim3(512), 106496, stream, wav, ws, mel);
  hipLaunchKernelGGL(k_ema, dim3(1024), dim3(256), 0, stream, mel, out);
  hipLaunchKernelGGL(k_mfcc, dim3(4, 64), dim3(256), 0, stream, mel, ws, out + 4100096);
}